// Round 3
// baseline (939.647 us; speedup 1.0000x reference)
//
#include <hip/hip_runtime.h>
#include <hip/hip_fp16.h>

#define N_NODES 500000
#define N_EDGES 5000000
#define D 16
#define BSHIFT 7
#define BSIZE 128
#define NB ((N_NODES + BSIZE - 1) / BSIZE)   // 3907 buckets of 128 nodes
#define CPAD 16                              // pad counters to 64B lines

// ---- K0: x (fp32) -> xh (fp16), streaming ---------------------------------
__global__ void tohalf_k(const float* __restrict__ x, __half2* __restrict__ xh) {
    int i = blockIdx.x * blockDim.x + threadIdx.x;     // one float4 per thread
    if (i >= (N_NODES * D) / 4) return;
    float4 v = ((const float4*)x)[i];
    xh[2 * i]     = __floats2half2_rn(v.x, v.y);
    xh[2 * i + 1] = __floats2half2_rn(v.z, v.w);
}

// ---- K1: bucket histogram (LDS-privatized) --------------------------------
__global__ __launch_bounds__(256) void hist_k(const int* __restrict__ edst,
                                              int* __restrict__ bhist) {
    __shared__ int h[NB];
    for (int i = threadIdx.x; i < NB; i += 256) h[i] = 0;
    __syncthreads();
    int stride = gridDim.x * blockDim.x;
    for (int e = blockIdx.x * blockDim.x + threadIdx.x; e < N_EDGES; e += stride)
        atomicAdd(&h[edst[e] >> BSHIFT], 1);
    __syncthreads();
    for (int i = threadIdx.x; i < NB; i += 256)
        if (h[i]) atomicAdd(&bhist[i * CPAD], h[i]);
}

// ---- K2: exclusive scan of 3907 bucket counts (1 block) -------------------
__global__ void scan_k(const int* __restrict__ bhist, int* __restrict__ boff,
                       int* __restrict__ bcur) {
    __shared__ int s[1024];
    int t = threadIdx.x;
    int v[4]; int sum = 0;
#pragma unroll
    for (int j = 0; j < 4; ++j) { int i = 4 * t + j; v[j] = (i < NB) ? bhist[i * CPAD] : 0; sum += v[j]; }
    s[t] = sum; __syncthreads();
    for (int off = 1; off < 1024; off <<= 1) {
        int u = (t >= off) ? s[t - off] : 0;
        __syncthreads(); s[t] += u; __syncthreads();
    }
    int base = s[t] - sum;
#pragma unroll
    for (int j = 0; j < 4; ++j) {
        int i = 4 * t + j;
        if (i < NB) { boff[i] = base; bcur[i * CPAD] = base; }
        base += v[j];
    }
    if (t == 1023) boff[NB] = s[1023];
}

// ---- K3: scatter edges into bucket-contiguous records ---------------------
// rec = (dst & 127) << 19 | src   (src < 2^19). Writes within a bucket are
// consecutive slots -> write frontier (3907 lines) stays L2-resident.
__global__ void binscatter_k(const int* __restrict__ esrc, const int* __restrict__ edst,
                             int* __restrict__ bcur, unsigned* __restrict__ rec) {
    int e = blockIdx.x * blockDim.x + threadIdx.x;
    if (e >= N_EDGES) return;
    int t = edst[e];
    int p = atomicAdd(&bcur[(t >> BSHIFT) * CPAD], 1);
    rec[p] = ((unsigned)(t & (BSIZE - 1)) << 19) | (unsigned)esrc[e];
}

// ---- K4: per-bucket LDS aggregation + fused mean/GEMV epilogue ------------
template <int USE_H>
__global__ __launch_bounds__(256) void reduce_k(
    const float* __restrict__ x, const __half* __restrict__ xh,
    const unsigned* __restrict__ rec, const int* __restrict__ boff,
    const float* __restrict__ Wl, const float* __restrict__ bl,
    const float* __restrict__ Wr, float* __restrict__ out) {
    __shared__ float slice[BSIZE * D];   // 8KB fp32 accumulator
    __shared__ int scnt[BSIZE];
    int tid = threadIdx.x;
    for (int i = tid; i < BSIZE * D; i += 256) slice[i] = 0.f;
    if (tid < BSIZE) scnt[tid] = 0;
    __syncthreads();

    int d = tid & 15, g = tid >> 4;      // 16 groups of 16 lanes
    float wl[D], wr[D];
    const float4* wl4 = (const float4*)(Wl + d * D);
    const float4* wr4 = (const float4*)(Wr + d * D);
#pragma unroll
    for (int q = 0; q < 4; ++q) {
        float4 a = wl4[q], b2 = wr4[q];
        wl[4*q]=a.x; wl[4*q+1]=a.y; wl[4*q+2]=a.z; wl[4*q+3]=a.w;
        wr[4*q]=b2.x; wr[4*q+1]=b2.y; wr[4*q+2]=b2.z; wr[4*q+3]=b2.w;
    }

    int b = blockIdx.x;
    int beg = boff[b], end = boff[b + 1];
    for (int r = beg + g; r < end; r += 16) {
        unsigned rc = rec[r];
        int src = (int)(rc & 0x7FFFFu);
        int nl  = (int)(rc >> 19);
        float v = USE_H ? __half2float(xh[src * D + d]) : x[src * D + d];
        atomicAdd(&slice[nl * D + d], v);
        if (d == 0) atomicAdd(&scnt[nl], 1);
    }
    __syncthreads();

    int node0 = b << BSHIFT;
    for (int n = g; n < BSIZE; n += 16) {
        int node = node0 + n;
        if (node >= N_NODES) continue;
        float m  = slice[n * D + d] / fmaxf((float)scnt[n], 1.f);
        float xv = x[node * D + d];
        float o  = bl[d];
#pragma unroll
        for (int k = 0; k < D; ++k)
            o += __shfl(m, k, 16) * wl[k] + __shfl(xv, k, 16) * wr[k];
        out[node * D + d] = o;
    }
}

// ===================== fallback (R1 atomic path, needs only 2MB ws) ========
__global__ void sage_scatter(const float* __restrict__ x, const int* __restrict__ esrc,
                             const int* __restrict__ edst, float* __restrict__ agg,
                             float* __restrict__ cnt) {
    long long gid = (long long)blockIdx.x * blockDim.x + threadIdx.x;
    long long e = gid >> 4;
    int d = (int)(gid & 15);
    if (e >= N_EDGES) return;
    atomicAdd(&agg[(long long)edst[e] * D + d], x[(long long)esrc[e] * D + d]);
    if (d == 0) atomicAdd(&cnt[edst[e]], 1.0f);
}

__global__ void sage_finalize(const float* __restrict__ x, float* __restrict__ agg_out,
                              const float* __restrict__ cnt, const float* __restrict__ W_l,
                              const float* __restrict__ b_l, const float* __restrict__ W_r) {
    __shared__ float sWl[D * D], sWr[D * D], sb[D];
    int tid = threadIdx.x;
    if (tid < D * D) { sWl[tid] = W_l[tid]; sWr[tid] = W_r[tid]; }
    if (tid < D) sb[tid] = b_l[tid];
    __syncthreads();
    int i = blockIdx.x * blockDim.x + tid;
    if (i >= N_NODES) return;
    float inv = 1.0f / fmaxf(cnt[i], 1.0f);
    float m[D], xv[D];
    const float4* ap = (const float4*)(agg_out + (long long)i * D);
    const float4* xp = (const float4*)(x + (long long)i * D);
#pragma unroll
    for (int q = 0; q < 4; ++q) {
        float4 a = ap[q], b = xp[q];
        m[4*q]=a.x*inv; m[4*q+1]=a.y*inv; m[4*q+2]=a.z*inv; m[4*q+3]=a.w*inv;
        xv[4*q]=b.x; xv[4*q+1]=b.y; xv[4*q+2]=b.z; xv[4*q+3]=b.w;
    }
    float o[D];
#pragma unroll
    for (int oo = 0; oo < D; ++oo) {
        float a2 = sb[oo];
#pragma unroll
        for (int k = 0; k < D; ++k) a2 += m[k]*sWl[oo*D+k] + xv[k]*sWr[oo*D+k];
        o[oo] = a2;
    }
    float4* op = (float4*)(agg_out + (long long)i * D);
#pragma unroll
    for (int q = 0; q < 4; ++q)
        op[q] = make_float4(o[4*q], o[4*q+1], o[4*q+2], o[4*q+3]);
}

// ===================== launch =====================
extern "C" void kernel_launch(void* const* d_in, const int* in_sizes, int n_in,
                              void* d_out, int out_size, void* d_ws, size_t ws_size,
                              hipStream_t stream) {
    const float* x   = (const float*)d_in[0];
    const int*   ei  = (const int*)d_in[1];
    const float* W_l = (const float*)d_in[2];
    const float* b_l = (const float*)d_in[3];
    const float* W_r = (const float*)d_in[4];
    const int* esrc = ei;
    const int* edst = ei + N_EDGES;
    float* out = (float*)d_out;

    // ws layout: rec(5M u32) | bhist(NB*16 int) | bcur(NB*16 int) | boff(NB+1) | xh(8M half)
    size_t rec_b  = (size_t)N_EDGES * 4;
    size_t pad_b  = (size_t)NB * CPAD * 4;
    size_t boff_b = (size_t)(NB + 1) * 4;
    size_t base_need = rec_b + 2 * pad_b + boff_b;
    size_t h_need    = base_need + (size_t)N_NODES * D * 2;

    if (ws_size >= base_need) {
        unsigned* rec  = (unsigned*)d_ws;
        int* bhist = (int*)((char*)d_ws + rec_b);
        int* bcur  = bhist + (size_t)NB * CPAD;
        int* boff  = bcur + (size_t)NB * CPAD;
        __half* xh = (__half*)((char*)d_ws + base_need);
        int use_h = (ws_size >= h_need);

        hipMemsetAsync(bhist, 0, pad_b, stream);
        if (use_h)
            tohalf_k<<<(N_NODES * D / 4 + 255) / 256, 256, 0, stream>>>(x, (__half2*)xh);
        hist_k<<<512, 256, 0, stream>>>(edst, bhist);
        scan_k<<<1, 1024, 0, stream>>>(bhist, boff, bcur);
        binscatter_k<<<(N_EDGES + 255) / 256, 256, 0, stream>>>(esrc, edst, bcur, rec);
        if (use_h)
            reduce_k<1><<<NB, 256, 0, stream>>>(x, xh, rec, boff, W_l, b_l, W_r, out);
        else
            reduce_k<0><<<NB, 256, 0, stream>>>(x, xh, rec, boff, W_l, b_l, W_r, out);
    } else {
        float* cntf = (float*)d_ws;
        hipMemsetAsync(out, 0, (size_t)N_NODES * D * sizeof(float), stream);
        hipMemsetAsync(cntf, 0, (size_t)N_NODES * sizeof(float), stream);
        long long total = (long long)N_EDGES * D;
        sage_scatter<<<(unsigned)((total + 255) / 256), 256, 0, stream>>>(x, esrc, edst, out, cntf);
        sage_finalize<<<(N_NODES + 255) / 256, 256, 0, stream>>>(x, out, cntf, W_l, b_l, W_r);
    }
}

// Round 4
// 594.962 us; speedup vs baseline: 1.5793x; 1.5793x over previous
//
#include <hip/hip_runtime.h>

#define N_NODES 500000
#define N_EDGES 5000000
#define D 16
#define BSH 9
#define BSZ 512                          // nodes per bucket
#define NB ((N_NODES + BSZ - 1) / BSZ)   // 977 buckets
#define CH 16384                         // edges per place-block chunk
#define PBLK ((N_EDGES + CH - 1) / CH)   // 306 blocks

// ---- K1: global bucket histogram (LDS-privatized) -------------------------
__global__ __launch_bounds__(256) void hist_k(const int* __restrict__ edst,
                                              int* __restrict__ bhist) {
    __shared__ int h[NB];
    for (int i = threadIdx.x; i < NB; i += 256) h[i] = 0;
    __syncthreads();
    int stride = gridDim.x * blockDim.x;
    for (int e = blockIdx.x * blockDim.x + threadIdx.x; e < N_EDGES; e += stride)
        atomicAdd(&h[edst[e] >> BSH], 1);
    __syncthreads();
    for (int i = threadIdx.x; i < NB; i += 256)
        if (h[i]) atomicAdd(&bhist[i], h[i]);
}

// ---- K2: exclusive scan of bucket totals (1 block) ------------------------
__global__ void scan_k(const int* __restrict__ bhist, int* __restrict__ boff,
                       int* __restrict__ cursor) {
    __shared__ int s[1024];
    int t = threadIdx.x;
    int v = (t < NB) ? bhist[t] : 0;
    s[t] = v; __syncthreads();
    for (int off = 1; off < 1024; off <<= 1) {
        int u = (t >= off) ? s[t - off] : 0;
        __syncthreads(); s[t] += u; __syncthreads();
    }
    if (t < NB) { int ex = s[t] - v; boff[t] = ex; cursor[t] = ex; }
    if (t == 0) boff[NB] = N_EDGES;
}

// ---- K3: bulk-reserve counting-sort placement -----------------------------
// Each block: LDS-count its chunk, reserve a PRIVATE contiguous segment per
// bucket (one atomicAdd of the whole count), then place records into owned
// segments -> no cross-block partial-line write sharing.
__global__ __launch_bounds__(256) void place_k(const int* __restrict__ esrc,
                                               const int* __restrict__ edst,
                                               int* __restrict__ cursor,
                                               unsigned* __restrict__ rec) {
    __shared__ int lc[NB];
    int t = threadIdx.x;
    for (int i = t; i < NB; i += 256) lc[i] = 0;
    __syncthreads();
    int e0 = blockIdx.x * CH;
    int e1 = e0 + CH; if (e1 > N_EDGES) e1 = N_EDGES;
    for (int e = e0 + t; e < e1; e += 256)
        atomicAdd(&lc[edst[e] >> BSH], 1);
    __syncthreads();
    for (int i = t; i < NB; i += 256) {
        int c = lc[i];
        if (c) lc[i] = atomicAdd(&cursor[i], c);   // lc[i] becomes global base
    }
    __syncthreads();
    for (int e = e0 + t; e < e1; e += 256) {
        int dd = edst[e];
        int b = dd >> BSH;
        int p = atomicAdd(&lc[b], 1);
        rec[p] = ((unsigned)(dd & (BSZ - 1)) << 19) | (unsigned)esrc[e];
    }
}

// ---- K4: per-bucket LDS aggregation + fused mean/GEMV epilogue ------------
// 512 threads = 32 groups of 16 lanes. Recs staged 1024-at-a-time into LDS
// (coalesced), then gather loop has fully independent x-row loads (MLP).
__global__ __launch_bounds__(512, 8) void reduce_k(
    const float* __restrict__ x, const unsigned* __restrict__ rec,
    const int* __restrict__ boff, const float* __restrict__ Wl,
    const float* __restrict__ bl, const float* __restrict__ Wr,
    float* __restrict__ out) {
    __shared__ float slice[BSZ * D];     // 32KB fp32 accumulator
    __shared__ int scnt[BSZ];            // 2KB
    __shared__ unsigned srec[1024];      // 4KB staging
    int t = threadIdx.x;
    for (int i = t; i < BSZ * D; i += 512) slice[i] = 0.f;
    for (int i = t; i < BSZ; i += 512) scnt[i] = 0;

    int d = t & 15, g = t >> 4;          // 32 groups
    int b = blockIdx.x;
    int beg = boff[b], end = boff[b + 1];

    for (int c0 = beg; c0 < end; c0 += 1024) {
        int cn = end - c0; if (cn > 1024) cn = 1024;
        __syncthreads();                  // also covers slice/scnt init
        for (int i = t; i < cn; i += 512) srec[i] = rec[c0 + i];
        __syncthreads();
#pragma unroll 4
        for (int i = g; i < cn; i += 32) {
            unsigned rc = srec[i];
            int src = (int)(rc & 0x7FFFFu);
            int nl  = (int)(rc >> 19);
            float v = x[src * D + d];              // 16 lanes -> one 64B row
            atomicAdd(&slice[nl * D + d], v);
            if (d == 0) atomicAdd(&scnt[nl], 1);
        }
    }
    __syncthreads();

    // epilogue: mean + out = mean@Wl^T + bl + x@Wr^T (weights loaded late
    // to keep gather-phase register pressure low)
    float wl[D], wr[D];
    const float4* wl4 = (const float4*)(Wl + d * D);
    const float4* wr4 = (const float4*)(Wr + d * D);
#pragma unroll
    for (int q = 0; q < 4; ++q) {
        float4 a = wl4[q], b2 = wr4[q];
        wl[4*q]=a.x; wl[4*q+1]=a.y; wl[4*q+2]=a.z; wl[4*q+3]=a.w;
        wr[4*q]=b2.x; wr[4*q+1]=b2.y; wr[4*q+2]=b2.z; wr[4*q+3]=b2.w;
    }
    float bb = bl[d];
    int node0 = b << BSH;
    for (int n = g; n < BSZ; n += 32) {
        int node = node0 + n;
        if (node >= N_NODES) break;       // uniform within 16-lane group
        float m  = slice[n * D + d] / fmaxf((float)scnt[n], 1.f);
        float xv = x[node * D + d];
        float o  = bb;
#pragma unroll
        for (int k = 0; k < D; ++k)
            o += __shfl(m, k, 16) * wl[k] + __shfl(xv, k, 16) * wr[k];
        out[node * D + d] = o;
    }
}

// ===================== fallback (R1 atomic path, needs only 2MB ws) ========
__global__ void sage_scatter(const float* __restrict__ x, const int* __restrict__ esrc,
                             const int* __restrict__ edst, float* __restrict__ agg,
                             float* __restrict__ cnt) {
    long long gid = (long long)blockIdx.x * blockDim.x + threadIdx.x;
    long long e = gid >> 4;
    int d = (int)(gid & 15);
    if (e >= N_EDGES) return;
    atomicAdd(&agg[(long long)edst[e] * D + d], x[(long long)esrc[e] * D + d]);
    if (d == 0) atomicAdd(&cnt[edst[e]], 1.0f);
}

__global__ void sage_finalize(const float* __restrict__ x, float* __restrict__ agg_out,
                              const float* __restrict__ cnt, const float* __restrict__ W_l,
                              const float* __restrict__ b_l, const float* __restrict__ W_r) {
    __shared__ float sWl[D * D], sWr[D * D], sb[D];
    int tid = threadIdx.x;
    if (tid < D * D) { sWl[tid] = W_l[tid]; sWr[tid] = W_r[tid]; }
    if (tid < D) sb[tid] = b_l[tid];
    __syncthreads();
    int i = blockIdx.x * blockDim.x + tid;
    if (i >= N_NODES) return;
    float inv = 1.0f / fmaxf(cnt[i], 1.0f);
    float m[D], xv[D];
    const float4* ap = (const float4*)(agg_out + (long long)i * D);
    const float4* xp = (const float4*)(x + (long long)i * D);
#pragma unroll
    for (int q = 0; q < 4; ++q) {
        float4 a = ap[q], b = xp[q];
        m[4*q]=a.x*inv; m[4*q+1]=a.y*inv; m[4*q+2]=a.z*inv; m[4*q+3]=a.w*inv;
        xv[4*q]=b.x; xv[4*q+1]=b.y; xv[4*q+2]=b.z; xv[4*q+3]=b.w;
    }
    float o[D];
#pragma unroll
    for (int oo = 0; oo < D; ++oo) {
        float a2 = sb[oo];
#pragma unroll
        for (int k = 0; k < D; ++k) a2 += m[k]*sWl[oo*D+k] + xv[k]*sWr[oo*D+k];
        o[oo] = a2;
    }
    float4* op = (float4*)(agg_out + (long long)i * D);
#pragma unroll
    for (int q = 0; q < 4; ++q)
        op[q] = make_float4(o[4*q], o[4*q+1], o[4*q+2], o[4*q+3]);
}

// ===================== launch =====================
extern "C" void kernel_launch(void* const* d_in, const int* in_sizes, int n_in,
                              void* d_out, int out_size, void* d_ws, size_t ws_size,
                              hipStream_t stream) {
    const float* x   = (const float*)d_in[0];
    const int*   ei  = (const int*)d_in[1];
    const float* W_l = (const float*)d_in[2];
    const float* b_l = (const float*)d_in[3];
    const float* W_r = (const float*)d_in[4];
    const int* esrc = ei;
    const int* edst = ei + N_EDGES;
    float* out = (float*)d_out;

    // ws layout: rec(5M u32) | bhist(NB) | boff(NB+1) | cursor(NB)
    size_t rec_b = (size_t)N_EDGES * 4;
    size_t need  = rec_b + (size_t)(3 * NB + 1) * 4;

    if (ws_size >= need) {
        unsigned* rec = (unsigned*)d_ws;
        int* bhist  = (int*)((char*)d_ws + rec_b);
        int* boff   = bhist + NB;
        int* cursor = boff + (NB + 1);

        hipMemsetAsync(bhist, 0, (size_t)NB * 4, stream);
        hist_k<<<512, 256, 0, stream>>>(edst, bhist);
        scan_k<<<1, 1024, 0, stream>>>(bhist, boff, cursor);
        place_k<<<PBLK, 256, 0, stream>>>(esrc, edst, cursor, rec);
        reduce_k<<<NB, 512, 0, stream>>>(x, rec, boff, W_l, b_l, W_r, out);
    } else {
        float* cntf = (float*)d_ws;
        hipMemsetAsync(out, 0, (size_t)N_NODES * D * sizeof(float), stream);
        hipMemsetAsync(cntf, 0, (size_t)N_NODES * sizeof(float), stream);
        long long total = (long long)N_EDGES * D;
        sage_scatter<<<(unsigned)((total + 255) / 256), 256, 0, stream>>>(x, esrc, edst, out, cntf);
        sage_finalize<<<(N_NODES + 255) / 256, 256, 0, stream>>>(x, out, cntf, W_l, b_l, W_r);
    }
}

// Round 5
// 594.294 us; speedup vs baseline: 1.5811x; 1.0011x over previous
//
#include <hip/hip_runtime.h>

#define N_NODES 500000
#define N_EDGES 5000000
#define D 16
#define BSH 9
#define BSZ 512                          // nodes per bucket
#define NB ((N_NODES + BSZ - 1) / BSZ)   // 977 buckets
#define CH 16384                         // edges per place-block chunk
#define PBLK ((N_EDGES + CH - 1) / CH)   // 306 blocks

// ---- K1: global bucket histogram (LDS-privatized) -------------------------
__global__ __launch_bounds__(256) void hist_k(const int* __restrict__ edst,
                                              int* __restrict__ bhist) {
    __shared__ int h[NB];
    for (int i = threadIdx.x; i < NB; i += 256) h[i] = 0;
    __syncthreads();
    int stride = gridDim.x * blockDim.x;
    for (int e = blockIdx.x * blockDim.x + threadIdx.x; e < N_EDGES; e += stride)
        atomicAdd(&h[edst[e] >> BSH], 1);
    __syncthreads();
    for (int i = threadIdx.x; i < NB; i += 256)
        if (h[i]) atomicAdd(&bhist[i], h[i]);
}

// ---- K2: exclusive scan of bucket totals (1 block) ------------------------
__global__ void scan_k(const int* __restrict__ bhist, int* __restrict__ boff,
                       int* __restrict__ cursor) {
    __shared__ int s[1024];
    int t = threadIdx.x;
    int v = (t < NB) ? bhist[t] : 0;
    s[t] = v; __syncthreads();
    for (int off = 1; off < 1024; off <<= 1) {
        int u = (t >= off) ? s[t - off] : 0;
        __syncthreads(); s[t] += u; __syncthreads();
    }
    if (t < NB) { int ex = s[t] - v; boff[t] = ex; cursor[t] = ex; }
    if (t == 0) boff[NB] = N_EDGES;
}

// ---- K3: bulk-reserve counting-sort placement -----------------------------
__global__ __launch_bounds__(256) void place_k(const int* __restrict__ esrc,
                                               const int* __restrict__ edst,
                                               int* __restrict__ cursor,
                                               unsigned* __restrict__ rec) {
    __shared__ int lc[NB];
    int t = threadIdx.x;
    for (int i = t; i < NB; i += 256) lc[i] = 0;
    __syncthreads();
    int e0 = blockIdx.x * CH;
    int e1 = e0 + CH; if (e1 > N_EDGES) e1 = N_EDGES;
    for (int e = e0 + t; e < e1; e += 256)
        atomicAdd(&lc[edst[e] >> BSH], 1);
    __syncthreads();
    for (int i = t; i < NB; i += 256) {
        int c = lc[i];
        if (c) lc[i] = atomicAdd(&cursor[i], c);   // lc[i] becomes global base
    }
    __syncthreads();
    for (int e = e0 + t; e < e1; e += 256) {
        int dd = edst[e];
        int b = dd >> BSH;
        int p = atomicAdd(&lc[b], 1);
        rec[p] = ((unsigned)(dd & (BSZ - 1)) << 19) | (unsigned)esrc[e];
    }
}

// ---- K4: per-bucket LDS aggregation, register-batched MLP gather ----------
// 512 threads = 32 groups of 16 lanes. Per batch, each group pulls 8 records
// into registers, issues 8 INDEPENDENT x-row loads (8x64B outstanding per
// group), then performs the 8 LDS atomic adds. Epilogue fuses mean + GEMVs.
__global__ __launch_bounds__(512, 8) void reduce_k(
    const float* __restrict__ x, const unsigned* __restrict__ rec,
    const int* __restrict__ boff, const float* __restrict__ Wl,
    const float* __restrict__ bl, const float* __restrict__ Wr,
    float* __restrict__ out) {
    __shared__ float slice[BSZ * D];     // 32KB fp32 accumulator
    __shared__ int scnt[BSZ];            // 2KB
    __shared__ unsigned srec[1024];      // 4KB staging
    int t = threadIdx.x;
    for (int i = t; i < BSZ * D; i += 512) slice[i] = 0.f;
    for (int i = t; i < BSZ; i += 512) scnt[i] = 0;

    int d = t & 15, g = t >> 4;          // 32 groups of 16 lanes
    int b = blockIdx.x;
    int beg = boff[b], end = boff[b + 1];

    for (int c0 = beg; c0 < end; c0 += 1024) {
        int cn = end - c0; if (cn > 1024) cn = 1024;
        __syncthreads();                  // also covers slice/scnt init
        for (int i = t; i < cn; i += 512) srec[i] = rec[c0 + i];
        __syncthreads();

        int nfull = cn >> 8;              // batches of 256 recs (8 per group)
        for (int bb = 0; bb < nfull; ++bb) {
            int base = bb * 256 + g * 8;
            unsigned rc[8];
#pragma unroll
            for (int j = 0; j < 8; ++j) rc[j] = srec[base + j];   // LDS broadcast
            float v[8];
#pragma unroll
            for (int j = 0; j < 8; ++j)
                v[j] = x[(int)(rc[j] & 0x7FFFFu) * D + d];        // 8 indep loads
#pragma unroll
            for (int j = 0; j < 8; ++j) {
                int nl = (int)(rc[j] >> 19);
                atomicAdd(&slice[nl * D + d], v[j]);
                if (d == 0) atomicAdd(&scnt[nl], 1);
            }
        }
        // tail (< 256 recs)
        for (int i = (nfull << 8) + g; i < cn; i += 32) {
            unsigned rc = srec[i];
            int src = (int)(rc & 0x7FFFFu);
            int nl  = (int)(rc >> 19);
            atomicAdd(&slice[nl * D + d], x[src * D + d]);
            if (d == 0) atomicAdd(&scnt[nl], 1);
        }
    }
    __syncthreads();

    // epilogue: mean + out = mean@Wl^T + bl + x@Wr^T
    float wl[D], wr[D];
    const float4* wl4 = (const float4*)(Wl + d * D);
    const float4* wr4 = (const float4*)(Wr + d * D);
#pragma unroll
    for (int q = 0; q < 4; ++q) {
        float4 a = wl4[q], b2 = wr4[q];
        wl[4*q]=a.x; wl[4*q+1]=a.y; wl[4*q+2]=a.z; wl[4*q+3]=a.w;
        wr[4*q]=b2.x; wr[4*q+1]=b2.y; wr[4*q+2]=b2.z; wr[4*q+3]=b2.w;
    }
    float bb = bl[d];
    int node0 = b << BSH;
    for (int n = g; n < BSZ; n += 32) {
        int node = node0 + n;
        if (node >= N_NODES) break;       // uniform within 16-lane group
        float m  = slice[n * D + d] / fmaxf((float)scnt[n], 1.f);
        float xv = x[node * D + d];
        float o  = bb;
#pragma unroll
        for (int k = 0; k < D; ++k)
            o += __shfl(m, k, 16) * wl[k] + __shfl(xv, k, 16) * wr[k];
        out[node * D + d] = o;
    }
}

// ===================== fallback (R1 atomic path, needs only 2MB ws) ========
__global__ void sage_scatter(const float* __restrict__ x, const int* __restrict__ esrc,
                             const int* __restrict__ edst, float* __restrict__ agg,
                             float* __restrict__ cnt) {
    long long gid = (long long)blockIdx.x * blockDim.x + threadIdx.x;
    long long e = gid >> 4;
    int d = (int)(gid & 15);
    if (e >= N_EDGES) return;
    atomicAdd(&agg[(long long)edst[e] * D + d], x[(long long)esrc[e] * D + d]);
    if (d == 0) atomicAdd(&cnt[edst[e]], 1.0f);
}

__global__ void sage_finalize(const float* __restrict__ x, float* __restrict__ agg_out,
                              const float* __restrict__ cnt, const float* __restrict__ W_l,
                              const float* __restrict__ b_l, const float* __restrict__ W_r) {
    __shared__ float sWl[D * D], sWr[D * D], sb[D];
    int tid = threadIdx.x;
    if (tid < D * D) { sWl[tid] = W_l[tid]; sWr[tid] = W_r[tid]; }
    if (tid < D) sb[tid] = b_l[tid];
    __syncthreads();
    int i = blockIdx.x * blockDim.x + tid;
    if (i >= N_NODES) return;
    float inv = 1.0f / fmaxf(cnt[i], 1.0f);
    float m[D], xv[D];
    const float4* ap = (const float4*)(agg_out + (long long)i * D);
    const float4* xp = (const float4*)(x + (long long)i * D);
#pragma unroll
    for (int q = 0; q < 4; ++q) {
        float4 a = ap[q], b = xp[q];
        m[4*q]=a.x*inv; m[4*q+1]=a.y*inv; m[4*q+2]=a.z*inv; m[4*q+3]=a.w*inv;
        xv[4*q]=b.x; xv[4*q+1]=b.y; xv[4*q+2]=b.z; xv[4*q+3]=b.w;
    }
    float o[D];
#pragma unroll
    for (int oo = 0; oo < D; ++oo) {
        float a2 = sb[oo];
#pragma unroll
        for (int k = 0; k < D; ++k) a2 += m[k]*sWl[oo*D+k] + xv[k]*sWr[oo*D+k];
        o[oo] = a2;
    }
    float4* op = (float4*)(agg_out + (long long)i * D);
#pragma unroll
    for (int q = 0; q < 4; ++q)
        op[q] = make_float4(o[4*q], o[4*q+1], o[4*q+2], o[4*q+3]);
}

// ===================== launch =====================
extern "C" void kernel_launch(void* const* d_in, const int* in_sizes, int n_in,
                              void* d_out, int out_size, void* d_ws, size_t ws_size,
                              hipStream_t stream) {
    const float* x   = (const float*)d_in[0];
    const int*   ei  = (const int*)d_in[1];
    const float* W_l = (const float*)d_in[2];
    const float* b_l = (const float*)d_in[3];
    const float* W_r = (const float*)d_in[4];
    const int* esrc = ei;
    const int* edst = ei + N_EDGES;
    float* out = (float*)d_out;

    // ws layout: rec(5M u32) | bhist(NB) | boff(NB+1) | cursor(NB)
    size_t rec_b = (size_t)N_EDGES * 4;
    size_t need  = rec_b + (size_t)(3 * NB + 1) * 4;

    if (ws_size >= need) {
        unsigned* rec = (unsigned*)d_ws;
        int* bhist  = (int*)((char*)d_ws + rec_b);
        int* boff   = bhist + NB;
        int* cursor = boff + (NB + 1);

        hipMemsetAsync(bhist, 0, (size_t)NB * 4, stream);
        hist_k<<<512, 256, 0, stream>>>(edst, bhist);
        scan_k<<<1, 1024, 0, stream>>>(bhist, boff, cursor);
        place_k<<<PBLK, 256, 0, stream>>>(esrc, edst, cursor, rec);
        reduce_k<<<NB, 512, 0, stream>>>(x, rec, boff, W_l, b_l, W_r, out);
    } else {
        float* cntf = (float*)d_ws;
        hipMemsetAsync(out, 0, (size_t)N_NODES * D * sizeof(float), stream);
        hipMemsetAsync(cntf, 0, (size_t)N_NODES * sizeof(float), stream);
        long long total = (long long)N_EDGES * D;
        sage_scatter<<<(unsigned)((total + 255) / 256), 256, 0, stream>>>(x, esrc, edst, out, cntf);
        sage_finalize<<<(N_NODES + 255) / 256, 256, 0, stream>>>(x, out, cntf, W_l, b_l, W_r);
    }
}